// Round 3
// baseline (782.510 us; speedup 1.0000x reference)
//
#include <hip/hip_runtime.h>

typedef unsigned short u16;
#define BATCH 16384

__device__ __forceinline__ float b2f(u16 u){ unsigned int i=((unsigned int)u)<<16; float f; __builtin_memcpy(&f,&i,4); return f; }
__device__ __forceinline__ u16 f2b(float f){ unsigned int x; __builtin_memcpy(&x,&f,4); unsigned int r=(x + 0x7fffu + ((x>>16)&1u))>>16; return (u16)r; }

// ---------------- zero fp32 buffer (graph-capture-safe memset) ----------------
__global__ __launch_bounds__(256) void zero_kernel(float* __restrict__ p, int n){
  int i = blockIdx.x*256 + threadIdx.x;
  if (i < n) p[i] = 0.f;
}

// ---------------- gather: e[b, f*16+d] = emb[f, ids[b,f], d] (f32 -> bf16) ----------------
__global__ __launch_bounds__(256) void gather_kernel(const int* __restrict__ ids,
                                                     const float* __restrict__ emb,
                                                     u16* __restrict__ e){
  int b = blockIdx.x; int tid = threadIdx.x;
  int f = tid >> 4, d = tid & 15;
  int id = ids[b*16 + f];
  e[(size_t)b*256 + tid] = f2b(emb[((size_t)f*100000 + (size_t)id)*16 + d]);
}

// ---------------- generic GEMM: C[M,N] = A[M,K] @ W[K,N] + bias ----------------
// A: bf16 workspace. W,bias: f32 global. fp32 accumulate, bf16 out.
// 64x64 tile, BK=32, 4x4 per thread.
#define BK 32
#define LSTR 68
__global__ __launch_bounds__(256) void gemm_kernel(const u16* __restrict__ A,
                                                   const float* __restrict__ W,
                                                   const float* __restrict__ bias,
                                                   u16* __restrict__ C,
                                                   int M, int N, int K){
  __shared__ float As[BK*LSTR];
  __shared__ float Bs[BK*LSTR];
  int tid = threadIdx.x;
  int n0 = blockIdx.x*64, m0 = blockIdx.y*64;
  int tx = tid & 15, ty = tid >> 4;
  int am = tid >> 2, ak = (tid & 3) * 8;   // A tile: 64 rows x 32 k, 8 bf16/thread
  int wk = tid >> 3, wn = (tid & 7) * 8;   // W tile: 32 k x 64 n, 8 f32/thread
  float acc[4][4] = {};
  for (int k0 = 0; k0 < K; k0 += BK){
    uint4 av = *(const uint4*)(A + (size_t)(m0+am)*K + (k0+ak));
    float4 w0 = make_float4(0.f,0.f,0.f,0.f), w1 = w0;
    if (n0 + wn < N){
      const float* wp = W + (size_t)(k0+wk)*N + (n0+wn);
      w0 = *(const float4*)wp;
      w1 = *(const float4*)(wp + 4);
    }
    u16 at[8]; __builtin_memcpy(at, &av, 16);
#pragma unroll
    for (int j=0;j<8;j++) As[(ak+j)*LSTR + am] = b2f(at[j]);
    float* bd = &Bs[wk*LSTR + wn];
    bd[0]=w0.x; bd[1]=w0.y; bd[2]=w0.z; bd[3]=w0.w;
    bd[4]=w1.x; bd[5]=w1.y; bd[6]=w1.z; bd[7]=w1.w;
    __syncthreads();
#pragma unroll
    for (int k=0;k<BK;k++){
      float4 a4 = *(const float4*)&As[k*LSTR + ty*4];
      float4 b4 = *(const float4*)&Bs[k*LSTR + tx*4];
      float aa[4] = {a4.x,a4.y,a4.z,a4.w};
      float bb[4] = {b4.x,b4.y,b4.z,b4.w};
#pragma unroll
      for (int i=0;i<4;i++)
#pragma unroll
        for (int j=0;j<4;j++) acc[i][j] += aa[i]*bb[j];
    }
    __syncthreads();
  }
  float bv[4];
#pragma unroll
  for (int j=0;j<4;j++){ int c = n0 + tx*4 + j; bv[j] = (bias != nullptr && c < N) ? bias[c] : 0.f; }
#pragma unroll
  for (int i=0;i<4;i++){
    int row = m0 + ty*4 + i;
#pragma unroll
    for (int j=0;j<4;j++){
      int c = n0 + tx*4 + j;
      if (c < N) C[(size_t)row*N + c] = f2b(acc[i][j] + bv[j]);
    }
  }
}

// ---------------- column stats (sum, sumsq) via atomics ----------------
__global__ __launch_bounds__(256) void colstats_kernel(const u16* __restrict__ Y,
                                                       float* __restrict__ sums,
                                                       float* __restrict__ sumsq,
                                                       int N, int rowsPerBlock){
  int tid = threadIdx.x;
  int r0 = blockIdx.x * rowsPerBlock;
  int cpt = (N + 255) >> 8;
  float s[4] = {0,0,0,0}, q[4] = {0,0,0,0};
  for (int r = r0; r < r0 + rowsPerBlock; ++r){
    for (int j=0;j<cpt;j++){
      int c = (j<<8) + tid;
      if (c < N){ float v = b2f(Y[(size_t)r*N + c]); s[j] += v; q[j] += v*v; }
    }
  }
  for (int j=0;j<cpt;j++){
    int c = (j<<8) + tid;
    if (c < N){ atomicAdd(&sums[c], s[j]); atomicAdd(&sumsq[c], q[j]); }
  }
}

// ---------------- finalize: scale/shift for BN (g, be are f32) ----------------
__global__ void finalize_kernel(const float* __restrict__ sums, const float* __restrict__ sumsq,
                                const float* __restrict__ g, const float* __restrict__ be,
                                float* __restrict__ scale, float* __restrict__ shift,
                                int N, int unbiased){
  int c = blockIdx.x*256 + threadIdx.x;
  if (c >= N) return;
  float mean = sums[c] / (float)BATCH;
  float var;
  if (unbiased) var = (sumsq[c] - mean*mean*(float)BATCH) / (float)(BATCH-1);
  else          var = sumsq[c] / (float)BATCH - mean*mean;
  float sc = g[c] * rsqrtf(var + 1e-5f);
  scale[c] = sc;
  shift[c] = be[c] - mean * sc;
}

// ---------------- BN + ReLU elementwise (in place) ----------------
__global__ __launch_bounds__(256) void bnrelu_kernel(u16* __restrict__ Y,
                                                     const float* __restrict__ scale,
                                                     const float* __restrict__ shift,
                                                     int Nmask, int total){
  int i = blockIdx.x*256 + threadIdx.x;
  if (i >= total) return;
  int c = i & Nmask;
  float v = b2f(Y[i]) * scale[c] + shift[c];
  Y[i] = f2b(v > 0.f ? v : 0.f);
}

// ---------------- cross network: 3 iters of x = e*(x.cw)+cb+x ----------------
__global__ __launch_bounds__(256) void cross_kernel(const u16* __restrict__ e,
                                                    const float* __restrict__ cw,
                                                    const float* __restrict__ cb,
                                                    u16* __restrict__ cn){
  __shared__ float red[4];
  int b = blockIdx.x, c = threadIdx.x;
  float ec = b2f(e[(size_t)b*256 + c]);
  float x = ec;
  for (int i=0;i<3;i++){
    float p = x * cw[i*256 + c];
#pragma unroll
    for (int o=32;o>0;o>>=1) p += __shfl_down(p, o, 64);
    if ((c & 63) == 0) red[c>>6] = p;
    __syncthreads();
    float dot = red[0] + red[1] + red[2] + red[3];
    __syncthreads();
    x = ec*dot + cb[i*256 + c] + x;
  }
  cn[(size_t)b*256 + c] = f2b(x);
}

// ---------------- fused adapter: per-row low-rank path through H ----------------
// 8 rows per block, 32 lanes per row. H,P bf16 ws; v0,u1,v1,ab0,ab1 f32 global.
__global__ __launch_bounds__(256) void adapter_kernel(const u16* __restrict__ H,
                                                      const u16* __restrict__ P,
                                                      const float* __restrict__ v0,
                                                      const float* __restrict__ u1,
                                                      const float* __restrict__ v1,
                                                      const float* __restrict__ ab0,
                                                      const float* __restrict__ ab1,
                                                      u16* __restrict__ T){
  __shared__ u16 Hs[8*1024];
  __shared__ u16 v1b[32*256];
  __shared__ float v0s[32*32];
  __shared__ float u1s[32*32];
  __shared__ float Ps[256], qs[256], t1s[256], ss[256], z2s[256];
  __shared__ float ab0s[32];
  __shared__ float ab1s[256];
  int tid = threadIdx.x;
  int r = tid >> 5, j = tid & 31;
  size_t row0 = (size_t)blockIdx.x * 8;

  for (int k = tid; k < 8*1024; k += 256) Hs[k] = H[row0*1024 + k];
  for (int k = tid; k < 1024; k += 256){ v0s[k] = v0[k]; u1s[k] = u1[k]; }
  for (int k = tid; k < 32*256; k += 256) v1b[k] = f2b(v1[k]);
  if (tid < 32) ab0s[tid] = ab0[tid];
  ab1s[tid] = ab1[tid];
  Ps[tid] = b2f(P[row0*32 + tid]);
  __syncthreads();

  // q[j] = sum_i P[i] * H[i,j]
  float acc = 0.f;
#pragma unroll
  for (int i=0;i<32;i++) acc += Ps[r*32+i] * b2f(Hs[r*1024 + i*32 + j]);
  qs[r*32+j] = acc;
  __syncthreads();

  // t1 = sigmoid(q @ v0 + ab0)
  acc = ab0s[j];
#pragma unroll
  for (int i=0;i<32;i++) acc += qs[r*32+i] * v0s[i*32+j];
  t1s[r*32+j] = 1.f / (1.f + __expf(-acc));
  __syncthreads();

  // s = t1 @ u1
  acc = 0.f;
#pragma unroll
  for (int i=0;i<32;i++) acc += t1s[r*32+i] * u1s[i*32+j];
  ss[r*32+j] = acc;
  __syncthreads();

  // z2[j] = sum_i s[i] * H[i,j]
  acc = 0.f;
#pragma unroll
  for (int i=0;i<32;i++) acc += ss[r*32+i] * b2f(Hs[r*1024 + i*32 + j]);
  z2s[r*32+j] = acc;
  __syncthreads();

  // t2 = z2 @ v1 + ab1  -> [256]
  for (int n = j; n < 256; n += 32){
    float a2 = ab1s[n];
#pragma unroll
    for (int i=0;i<32;i++) a2 += z2s[r*32+i] * b2f(v1b[i*256 + n]);
    T[(row0 + r)*256 + n] = f2b(a2);
  }
}

// ---------------- final head: BN(t)+residual, concat dot with lw, sigmoid ----------------
__global__ __launch_bounds__(256) void final_kernel(const u16* __restrict__ cn,
                                                    const u16* __restrict__ t,
                                                    const u16* __restrict__ mo,
                                                    const float* __restrict__ aT,
                                                    const float* __restrict__ bT,
                                                    const float* __restrict__ lw,
                                                    const float* __restrict__ lb,
                                                    float* __restrict__ out){
  int wave = threadIdx.x >> 6, lane = threadIdx.x & 63;
  int b = blockIdx.x*4 + wave;
  float p = 0.f;
  for (int n = lane; n < 256; n += 64){
    p += b2f(cn[(size_t)b*256 + n]) * lw[n];
    float mf = aT[n]*b2f(t[(size_t)b*256 + n]) + bT[n] + b2f(mo[(size_t)b*256 + n]);
    p += mf * lw[256 + n];
  }
#pragma unroll
  for (int o=32;o>0;o>>=1) p += __shfl_down(p, o, 64);
  if (lane == 0){
    float y = p + lb[0];
    out[b] = 1.f / (1.f + __expf(-y));
  }
}

extern "C" void kernel_launch(void* const* d_in, const int* in_sizes, int n_in,
                              void* d_out, int out_size, void* d_ws, size_t ws_size,
                              hipStream_t stream) {
  const int B = BATCH;
  const int*   feat = (const int*)d_in[0];
  const float* emb  = (const float*)d_in[2];
  const float* hW0 = (const float*)d_in[3],  *hb0 = (const float*)d_in[4],  *hg0 = (const float*)d_in[5],  *hbe0 = (const float*)d_in[6];
  const float* hW1 = (const float*)d_in[7],  *hb1 = (const float*)d_in[8],  *hg1 = (const float*)d_in[9],  *hbe1 = (const float*)d_in[10];
  const float* hW2 = (const float*)d_in[11], *hb2 = (const float*)d_in[12], *hg2 = (const float*)d_in[13], *hbe2 = (const float*)d_in[14];
  const float* cw  = (const float*)d_in[15], *cb  = (const float*)d_in[16];
  const float* mW0 = (const float*)d_in[17], *mb0 = (const float*)d_in[18], *mg0 = (const float*)d_in[19], *mbe0 = (const float*)d_in[20];
  const float* mW1 = (const float*)d_in[21], *mb1 = (const float*)d_in[22], *mg1 = (const float*)d_in[23], *mbe1 = (const float*)d_in[24];
  const float* u0  = (const float*)d_in[25], *u1  = (const float*)d_in[26];
  const float* v0  = (const float*)d_in[27], *v1  = (const float*)d_in[28];
  const float* ab0 = (const float*)d_in[29], *ab1 = (const float*)d_in[30];
  const float* gamma1 = (const float*)d_in[31], *bias1 = (const float*)d_in[32];
  const float* lw  = (const float*)d_in[33], *lb = (const float*)d_in[34];
  float* out = (float*)d_out;

  // ---- aliased workspace layout (64 MB + 16 KB total), bf16 activations ----
  // [ 0M,32M): H
  // [32M,40M): e (dead after M0-gemm & cross) -> T
  // [40M,56M): Y0[0,4M)+Y1[4M,6M) -> M0 -> cn[0,8M)+P[8M,9M)
  // [56M,64M): Mout
  // [64M,+16KB): stats
  char* base = (char*)d_ws;
  const size_t MB = 1024*1024;
  u16* H    = (u16*)(base);
  u16* e    = (u16*)(base + 32*MB);
  u16* T    = (u16*)(base + 32*MB);   // aliases e (e dead before adapter writes T)
  u16* Y0   = (u16*)(base + 40*MB);
  u16* Y1   = (u16*)(base + 44*MB);
  u16* M0   = (u16*)(base + 40*MB);   // aliases Y0/Y1 (dead before M0 written)
  u16* cn   = (u16*)(base + 40*MB);   // aliases M0 (dead before cn written)
  u16* P    = (u16*)(base + 48*MB);
  u16* Mout = (u16*)(base + 56*MB);
  float* sums  = (float*)(base + 64*MB);
  float* sumsq = sums + 1024;
  float* scale = sums + 2048;
  float* shift = sums + 3072;

  auto bn_block = [&](u16* Y, int N, const float* g, const float* be, int unbiased){
    zero_kernel<<<8, 256, 0, stream>>>(sums, 2048);     // zeroes sums+sumsq
    colstats_kernel<<<B/64, 256, 0, stream>>>(Y, sums, sumsq, N, 64);
    finalize_kernel<<<(N+255)/256, 256, 0, stream>>>(sums, sumsq, g, be, scale, shift, N, unbiased);
  };

  // 1. gather
  gather_kernel<<<B, 256, 0, stream>>>(feat, emb, e);

  // 2. hyper chain -> H
  gemm_kernel<<<dim3(2, B/64), 256, 0, stream>>>(e, hW0, hb0, Y0, B, 128, 256);
  bn_block(Y0, 128, hg0, hbe0, 0);
  bnrelu_kernel<<<(B*128)/256, 256, 0, stream>>>(Y0, scale, shift, 127, B*128);

  gemm_kernel<<<dim3(1, B/64), 256, 0, stream>>>(Y0, hW1, hb1, Y1, B, 64, 128);
  bn_block(Y1, 64, hg1, hbe1, 0);
  bnrelu_kernel<<<(B*64)/256, 256, 0, stream>>>(Y1, scale, shift, 63, B*64);

  gemm_kernel<<<dim3(16, B/64), 256, 0, stream>>>(Y1, hW2, hb2, H, B, 1024, 64);
  bn_block(H, 1024, hg2, hbe2, 0);
  bnrelu_kernel<<<(B*1024)/256, 256, 0, stream>>>(H, scale, shift, 1023, B*1024);

  // 3. MLP chain (Y0/Y1 dead; M0 overwrites their region)
  gemm_kernel<<<dim3(8, B/64), 256, 0, stream>>>(e, mW0, mb0, M0, B, 512, 256);
  bn_block(M0, 512, mg0, mbe0, 0);
  bnrelu_kernel<<<(B*512)/256, 256, 0, stream>>>(M0, scale, shift, 511, B*512);

  gemm_kernel<<<dim3(4, B/64), 256, 0, stream>>>(M0, mW1, mb1, Mout, B, 256, 512);
  bn_block(Mout, 256, mg1, mbe1, 0);
  bnrelu_kernel<<<(B*256)/256, 256, 0, stream>>>(Mout, scale, shift, 255, B*256);

  // 4. cross network (M0 dead; cn overwrites its region; e still live)
  cross_kernel<<<B, 256, 0, stream>>>(e, cw, cb, cn);

  // 5. adapter: P = Mout@u0, then fused low-rank path (T overwrites e region)
  gemm_kernel<<<dim3(1, B/64), 256, 0, stream>>>(Mout, u0, nullptr, P, B, 32, 256);
  adapter_kernel<<<B/8, 256, 0, stream>>>(H, P, v0, u1, v1, ab0, ab1, T);

  // 6. unbiased BN on t (gamma1/bias1), then final head
  bn_block(T, 256, gamma1, bias1, 1);
  final_kernel<<<B/4, 256, 0, stream>>>(cn, T, Mout, scale, shift, lw, lb, out);
}

// Round 4
// 524.387 us; speedup vs baseline: 1.4922x; 1.4922x over previous
//
#include <hip/hip_runtime.h>

typedef unsigned short u16;
#define BATCH 16384

__device__ __forceinline__ float b2f(u16 u){ unsigned int i=((unsigned int)u)<<16; float f; __builtin_memcpy(&f,&i,4); return f; }
__device__ __forceinline__ u16 f2b(float f){ unsigned int x; __builtin_memcpy(&x,&f,4); unsigned int r=(x + 0x7fffu + ((x>>16)&1u))>>16; return (u16)r; }

// ---------------- zero fp32 buffer (graph-capture-safe memset) ----------------
__global__ __launch_bounds__(256) void zero_kernel(float* __restrict__ p, int n){
  int i = blockIdx.x*256 + threadIdx.x;
  if (i < n) p[i] = 0.f;
}

// ---------------- gather: e[b, f*16+d] = emb[f, ids[b,f], d] (f32 -> bf16) ----------------
__global__ __launch_bounds__(256) void gather_kernel(const int* __restrict__ ids,
                                                     const float* __restrict__ emb,
                                                     u16* __restrict__ e){
  int b = blockIdx.x; int tid = threadIdx.x;
  int f = tid >> 4, d = tid & 15;
  int id = ids[b*16 + f];
  e[(size_t)b*256 + tid] = f2b(emb[((size_t)f*100000 + (size_t)id)*16 + d]);
}

// ---------------- GEMM: C = act(A) @ W + bias, with optional fused BN-on-A and
// fused column-stats epilogue (sum, sumsq of the f32 output) -----------------
// A: bf16 ws (raw pre-BN). ascale/ashift: BN(A) params (nullptr = identity).
// W,bias f32 global. C bf16 raw out. sums/sumsq: per-column stats (nullptr=skip).
// 64x64 tile, BK=32, 4x4 per thread.
#define BK 32
#define LSTR 68
__global__ __launch_bounds__(256) void gemm_kernel(const u16* __restrict__ A,
                                                   const float* __restrict__ W,
                                                   const float* __restrict__ bias,
                                                   u16* __restrict__ C,
                                                   const float* __restrict__ ascale,
                                                   const float* __restrict__ ashift,
                                                   float* __restrict__ sums,
                                                   float* __restrict__ sumsq,
                                                   int M, int N, int K){
  __shared__ float As[BK*LSTR];
  __shared__ float Bs[BK*LSTR];
  int tid = threadIdx.x;
  int n0 = blockIdx.x*64, m0 = blockIdx.y*64;
  int tx = tid & 15, ty = tid >> 4;
  int am = tid >> 2, ak = (tid & 3) * 8;   // A tile: 64 rows x 32 k, 8 bf16/thread
  int wk = tid >> 3, wn = (tid & 7) * 8;   // W tile: 32 k x 64 n, 8 f32/thread
  float acc[4][4] = {};
  for (int k0 = 0; k0 < K; k0 += BK){
    uint4 av = *(const uint4*)(A + (size_t)(m0+am)*K + (k0+ak));
    float4 w0 = make_float4(0.f,0.f,0.f,0.f), w1 = w0;
    if (n0 + wn < N){
      const float* wp = W + (size_t)(k0+wk)*N + (n0+wn);
      w0 = *(const float4*)wp;
      w1 = *(const float4*)(wp + 4);
    }
    u16 at[8]; __builtin_memcpy(at, &av, 16);
    if (ascale != nullptr){
#pragma unroll
      for (int j=0;j<8;j++){
        float v = b2f(at[j]) * ascale[k0+ak+j] + ashift[k0+ak+j];
        As[(ak+j)*LSTR + am] = v > 0.f ? v : 0.f;
      }
    } else {
#pragma unroll
      for (int j=0;j<8;j++) As[(ak+j)*LSTR + am] = b2f(at[j]);
    }
    float* bd = &Bs[wk*LSTR + wn];
    bd[0]=w0.x; bd[1]=w0.y; bd[2]=w0.z; bd[3]=w0.w;
    bd[4]=w1.x; bd[5]=w1.y; bd[6]=w1.z; bd[7]=w1.w;
    __syncthreads();
#pragma unroll
    for (int k=0;k<BK;k++){
      float4 a4 = *(const float4*)&As[k*LSTR + ty*4];
      float4 b4 = *(const float4*)&Bs[k*LSTR + tx*4];
      float aa[4] = {a4.x,a4.y,a4.z,a4.w};
      float bb[4] = {b4.x,b4.y,b4.z,b4.w};
#pragma unroll
      for (int i=0;i<4;i++)
#pragma unroll
        for (int j=0;j<4;j++) acc[i][j] += aa[i]*bb[j];
    }
    __syncthreads();
  }
  float bv[4];
#pragma unroll
  for (int j=0;j<4;j++){ int c = n0 + tx*4 + j; bv[j] = (bias != nullptr && c < N) ? bias[c] : 0.f; }
  float cs[4] = {0,0,0,0}, cq[4] = {0,0,0,0};
#pragma unroll
  for (int i=0;i<4;i++){
    int row = m0 + ty*4 + i;
#pragma unroll
    for (int j=0;j<4;j++){
      int c = n0 + tx*4 + j;
      float v = acc[i][j] + bv[j];
      if (c < N) C[(size_t)row*N + c] = f2b(v);
      cs[j] += v; cq[j] += v*v;
    }
  }
  if (sums != nullptr){
    // per-column reduction across the 16 ty groups via LDS (reuse As/Bs)
#pragma unroll
    for (int j=0;j<4;j++){ As[ty*64 + tx*4 + j] = cs[j]; Bs[ty*64 + tx*4 + j] = cq[j]; }
    __syncthreads();
    if (tid < 64){
      float ss = 0.f, qq = 0.f;
#pragma unroll
      for (int t=0;t<16;t++){ ss += As[t*64 + tid]; qq += Bs[t*64 + tid]; }
      int c = n0 + tid;
      if (c < N){ atomicAdd(&sums[c], ss); atomicAdd(&sumsq[c], qq); }
    }
  }
}

// ---------------- finalize: biased batch stats -> scale/shift ----------------
__global__ void finalize_kernel(const float* __restrict__ sums, const float* __restrict__ sumsq,
                                const float* __restrict__ g, const float* __restrict__ be,
                                float* __restrict__ scale, float* __restrict__ shift, int N){
  int c = blockIdx.x*256 + threadIdx.x;
  if (c >= N) return;
  float mean = sums[c] / (float)BATCH;
  float var  = sumsq[c] / (float)BATCH - mean*mean;
  float sc = g[c] * rsqrtf(var + 1e-5f);
  scale[c] = sc;
  shift[c] = be[c] - mean * sc;
}

// ---------------- finalize for T: 8 staged copies, unbiased variance ----------------
__global__ void finalizeT_kernel(const float* __restrict__ tpart,
                                 const float* __restrict__ g, const float* __restrict__ be,
                                 float* __restrict__ scale, float* __restrict__ shift){
  int c = threadIdx.x;  // 256
  float s = 0.f, q = 0.f;
#pragma unroll
  for (int k=0;k<8;k++){ s += tpart[k*512 + c]; q += tpart[k*512 + c + 256]; }
  float mean = s / (float)BATCH;
  float var  = (q - mean*mean*(float)BATCH) / (float)(BATCH-1);
  float sc = g[c] * rsqrtf(var + 1e-5f);
  scale[c] = sc;
  shift[c] = be[c] - mean * sc;
}

// ---------------- cross network: 3 iters of x = e*(x.cw)+cb+x ----------------
__global__ __launch_bounds__(256) void cross_kernel(const u16* __restrict__ e,
                                                    const float* __restrict__ cw,
                                                    const float* __restrict__ cb,
                                                    u16* __restrict__ cn){
  __shared__ float red[4];
  int b = blockIdx.x, c = threadIdx.x;
  float ec = b2f(e[(size_t)b*256 + c]);
  float x = ec;
  for (int i=0;i<3;i++){
    float p = x * cw[i*256 + c];
#pragma unroll
    for (int o=32;o>0;o>>=1) p += __shfl_down(p, o, 64);
    if ((c & 63) == 0) red[c>>6] = p;
    __syncthreads();
    float dot = red[0] + red[1] + red[2] + red[3];
    __syncthreads();
    x = ec*dot + cb[i*256 + c] + x;
  }
  cn[(size_t)b*256 + c] = f2b(x);
}

// ---------------- fused adapter: BN(H) on load, low-rank path, T-stats epilogue --------
// 8 rows per block, 32 lanes per row.
__global__ __launch_bounds__(256) void adapter_kernel(const u16* __restrict__ H,
                                                      const u16* __restrict__ P,
                                                      const float* __restrict__ v0,
                                                      const float* __restrict__ u1,
                                                      const float* __restrict__ v1,
                                                      const float* __restrict__ ab0,
                                                      const float* __restrict__ ab1,
                                                      const float* __restrict__ hscale,
                                                      const float* __restrict__ hshift,
                                                      float* __restrict__ tpart,
                                                      u16* __restrict__ T){
  __shared__ __align__(16) u16 Hs[8*1024];   // later reused as f32 tpart scratch (16KB)
  __shared__ u16 v1b[32*256];
  __shared__ float v0s[32*32];
  __shared__ float u1s[32*32];
  __shared__ float Ps[256], qs[256], t1s[256], ss[256], z2s[256];
  __shared__ float ab0s[32];
  __shared__ float ab1s[256];
  int tid = threadIdx.x;
  int r = tid >> 5, j = tid & 31;
  size_t row0 = (size_t)blockIdx.x * 8;

  for (int k = tid; k < 8*1024; k += 256){
    int col = k & 1023;
    float v = b2f(H[row0*1024 + k]) * hscale[col] + hshift[col];
    Hs[k] = f2b(v > 0.f ? v : 0.f);
  }
  for (int k = tid; k < 1024; k += 256){ v0s[k] = v0[k]; u1s[k] = u1[k]; }
  for (int k = tid; k < 32*256; k += 256) v1b[k] = f2b(v1[k]);
  if (tid < 32) ab0s[tid] = ab0[tid];
  ab1s[tid] = ab1[tid];
  Ps[tid] = b2f(P[row0*32 + tid]);
  __syncthreads();

  // q[j] = sum_i P[i] * H[i,j]
  float acc = 0.f;
#pragma unroll
  for (int i=0;i<32;i++) acc += Ps[r*32+i] * b2f(Hs[r*1024 + i*32 + j]);
  qs[r*32+j] = acc;
  __syncthreads();

  // t1 = sigmoid(q @ v0 + ab0)
  acc = ab0s[j];
#pragma unroll
  for (int i=0;i<32;i++) acc += qs[r*32+i] * v0s[i*32+j];
  t1s[r*32+j] = 1.f / (1.f + __expf(-acc));
  __syncthreads();

  // s = t1 @ u1
  acc = 0.f;
#pragma unroll
  for (int i=0;i<32;i++) acc += t1s[r*32+i] * u1s[i*32+j];
  ss[r*32+j] = acc;
  __syncthreads();

  // z2[j] = sum_i s[i] * H[i,j]
  acc = 0.f;
#pragma unroll
  for (int i=0;i<32;i++) acc += ss[r*32+i] * b2f(Hs[r*1024 + i*32 + j]);
  z2s[r*32+j] = acc;
  __syncthreads();          // Hs dead from here; reuse its LDS for T partials

  float* tp = (float*)Hs;          // [8][256] values
  float* tq = tp + 2048;           // [8][256] squares
  // t2 = z2 @ v1 + ab1  -> [256]
  for (int n = j; n < 256; n += 32){
    float a2 = ab1s[n];
#pragma unroll
    for (int i=0;i<32;i++) a2 += z2s[r*32+i] * b2f(v1b[i*256 + n]);
    T[(row0 + r)*256 + n] = f2b(a2);
    tp[r*256 + n] = a2;
    tq[r*256 + n] = a2*a2;
  }
  __syncthreads();
  // column reduce over the 8 rows, stage into 8 contention-splitting copies
  {
    int c = tid;
    float s8 = 0.f, q8 = 0.f;
#pragma unroll
    for (int rr=0;rr<8;rr++){ s8 += tp[rr*256 + c]; q8 += tq[rr*256 + c]; }
    float* dst = tpart + (size_t)(blockIdx.x & 7) * 512;
    atomicAdd(&dst[c], s8);
    atomicAdd(&dst[c + 256], q8);
  }
}

// ---------------- final head: BN(t), BN+ReLU(Mout), residual, concat-dot, sigmoid ------
__global__ __launch_bounds__(256) void final_kernel(const u16* __restrict__ cn,
                                                    const u16* __restrict__ t,
                                                    const u16* __restrict__ mo,
                                                    const float* __restrict__ tS,
                                                    const float* __restrict__ tB,
                                                    const float* __restrict__ mS,
                                                    const float* __restrict__ mB,
                                                    const float* __restrict__ lw,
                                                    const float* __restrict__ lb,
                                                    float* __restrict__ out){
  int wave = threadIdx.x >> 6, lane = threadIdx.x & 63;
  int b = blockIdx.x*4 + wave;
  float p = 0.f;
  for (int n = lane; n < 256; n += 64){
    p += b2f(cn[(size_t)b*256 + n]) * lw[n];
    float mr = b2f(mo[(size_t)b*256 + n]) * mS[n] + mB[n];   // BN(Mout)
    mr = mr > 0.f ? mr : 0.f;                                 // ReLU
    float mf = tS[n]*b2f(t[(size_t)b*256 + n]) + tB[n] + mr;  // BN(t) + residual
    p += mf * lw[256 + n];
  }
#pragma unroll
  for (int o=32;o>0;o>>=1) p += __shfl_down(p, o, 64);
  if (lane == 0){
    float y = p + lb[0];
    out[b] = 1.f / (1.f + __expf(-y));
  }
}

extern "C" void kernel_launch(void* const* d_in, const int* in_sizes, int n_in,
                              void* d_out, int out_size, void* d_ws, size_t ws_size,
                              hipStream_t stream) {
  const int B = BATCH;
  const int*   feat = (const int*)d_in[0];
  const float* emb  = (const float*)d_in[2];
  const float* hW0 = (const float*)d_in[3],  *hb0 = (const float*)d_in[4],  *hg0 = (const float*)d_in[5],  *hbe0 = (const float*)d_in[6];
  const float* hW1 = (const float*)d_in[7],  *hb1 = (const float*)d_in[8],  *hg1 = (const float*)d_in[9],  *hbe1 = (const float*)d_in[10];
  const float* hW2 = (const float*)d_in[11], *hb2 = (const float*)d_in[12], *hg2 = (const float*)d_in[13], *hbe2 = (const float*)d_in[14];
  const float* cw  = (const float*)d_in[15], *cb  = (const float*)d_in[16];
  const float* mW0 = (const float*)d_in[17], *mb0 = (const float*)d_in[18], *mg0 = (const float*)d_in[19], *mbe0 = (const float*)d_in[20];
  const float* mW1 = (const float*)d_in[21], *mb1 = (const float*)d_in[22], *mg1 = (const float*)d_in[23], *mbe1 = (const float*)d_in[24];
  const float* u0  = (const float*)d_in[25], *u1  = (const float*)d_in[26];
  const float* v0  = (const float*)d_in[27], *v1  = (const float*)d_in[28];
  const float* ab0 = (const float*)d_in[29], *ab1 = (const float*)d_in[30];
  const float* gamma1 = (const float*)d_in[31], *bias1 = (const float*)d_in[32];
  const float* lw  = (const float*)d_in[33], *lb = (const float*)d_in[34];
  float* out = (float*)d_out;

  // ---- aliased workspace layout (64 MB + 104 KB), bf16 activations ----
  // [ 0M,32M): H (raw)
  // [32M,40M): e -> T (raw)
  // [40M,56M): Y0[0,4M)+Y1[4M,6M) -> M0 -> cn[0,8M)+P[8M,9M)
  // [56M,64M): Mout (raw)
  // [64M, ..): stats: sums/sumsq L0..L4 (5*2048 f32), Tpart (8*512 f32),
  //            then scale/shift L0..L5 (6*2048 f32)
  char* base = (char*)d_ws;
  const size_t MB = 1024*1024;
  u16* H    = (u16*)(base);
  u16* e    = (u16*)(base + 32*MB);
  u16* T    = (u16*)(base + 32*MB);
  u16* Y0   = (u16*)(base + 40*MB);
  u16* Y1   = (u16*)(base + 44*MB);
  u16* M0   = (u16*)(base + 40*MB);
  u16* cn   = (u16*)(base + 40*MB);
  u16* P    = (u16*)(base + 48*MB);
  u16* Mout = (u16*)(base + 56*MB);
  float* S  = (float*)(base + 64*MB);
  // sums/sumsq per layer l=0..4
  auto sums  = [&](int l){ return S + l*2048; };
  auto sumsq = [&](int l){ return S + l*2048 + 1024; };
  float* tpart = S + 10240;                 // 8 copies x [256 sum | 256 sq]
  float* SS = S + 14336;
  auto scl = [&](int l){ return SS + l*2048; };
  auto shf = [&](int l){ return SS + l*2048 + 1024; };

  // zero all stats accumulators (14336 floats)
  zero_kernel<<<56, 256, 0, stream>>>(S, 14336);

  // 1. gather
  gather_kernel<<<B, 256, 0, stream>>>(feat, emb, e);

  // 2. hyper chain -> H   (stats fused into each GEMM, BN-apply fused into next load)
  gemm_kernel<<<dim3(2, B/64), 256, 0, stream>>>(e,  hW0, hb0, Y0, nullptr, nullptr, sums(0), sumsq(0), B, 128, 256);
  finalize_kernel<<<1, 256, 0, stream>>>(sums(0), sumsq(0), hg0, hbe0, scl(0), shf(0), 128);

  gemm_kernel<<<dim3(1, B/64), 256, 0, stream>>>(Y0, hW1, hb1, Y1, scl(0), shf(0), sums(1), sumsq(1), B, 64, 128);
  finalize_kernel<<<1, 256, 0, stream>>>(sums(1), sumsq(1), hg1, hbe1, scl(1), shf(1), 64);

  gemm_kernel<<<dim3(16, B/64), 256, 0, stream>>>(Y1, hW2, hb2, H, scl(1), shf(1), sums(2), sumsq(2), B, 1024, 64);
  finalize_kernel<<<4, 256, 0, stream>>>(sums(2), sumsq(2), hg2, hbe2, scl(2), shf(2), 1024);

  // 3. MLP chain
  gemm_kernel<<<dim3(8, B/64), 256, 0, stream>>>(e,  mW0, mb0, M0, nullptr, nullptr, sums(3), sumsq(3), B, 512, 256);
  finalize_kernel<<<2, 256, 0, stream>>>(sums(3), sumsq(3), mg0, mbe0, scl(3), shf(3), 512);

  gemm_kernel<<<dim3(4, B/64), 256, 0, stream>>>(M0, mW1, mb1, Mout, scl(3), shf(3), sums(4), sumsq(4), B, 256, 512);
  finalize_kernel<<<1, 256, 0, stream>>>(sums(4), sumsq(4), mg1, mbe1, scl(4), shf(4), 256);

  // 4. cross network (M0 dead; cn overwrites; e still live)
  cross_kernel<<<B, 256, 0, stream>>>(e, cw, cb, cn);

  // 5. adapter: P = BN_relu(Mout)@u0, then fused low-rank path (T overwrites e)
  gemm_kernel<<<dim3(1, B/64), 256, 0, stream>>>(Mout, u0, nullptr, P, scl(4), shf(4), nullptr, nullptr, B, 32, 256);
  adapter_kernel<<<B/8, 256, 0, stream>>>(H, P, v0, u1, v1, ab0, ab1, scl(2), shf(2), tpart, T);

  // 6. unbiased BN stats for T, then final head
  finalizeT_kernel<<<1, 256, 0, stream>>>(tpart, gamma1, bias1, scl(5), shf(5));
  final_kernel<<<B/4, 256, 0, stream>>>(cn, T, Mout, scl(5), shf(5), scl(4), shf(4), lw, lb, out);
}

// Round 5
// 409.738 us; speedup vs baseline: 1.9098x; 1.2798x over previous
//
#include <hip/hip_runtime.h>

typedef unsigned short u16;
typedef __attribute__((ext_vector_type(8))) short bf16x8;
typedef __attribute__((ext_vector_type(4))) float f32x4;
#define BATCH 16384

__device__ __forceinline__ float b2f(u16 u){ unsigned int i=((unsigned int)u)<<16; float f; __builtin_memcpy(&f,&i,4); return f; }
__device__ __forceinline__ u16 f2b(float f){ unsigned int x; __builtin_memcpy(&x,&f,4); unsigned int r=(x + 0x7fffu + ((x>>16)&1u))>>16; return (u16)r; }

// ---------------- zero fp32 buffer (graph-capture-safe memset) ----------------
__global__ __launch_bounds__(256) void zero_kernel(float* __restrict__ p, int n){
  int i = blockIdx.x*256 + threadIdx.x;
  if (i < n) p[i] = 0.f;
}

// ---------------- one-shot: transpose+convert all 6 weights to bf16 [N][K] ----------------
__global__ __launch_bounds__(256) void transpose_weights(const float* __restrict__ w0, const float* __restrict__ w1,
                                                         const float* __restrict__ w2, const float* __restrict__ w3,
                                                         const float* __restrict__ w4, const float* __restrict__ w5,
                                                         u16* __restrict__ t0, u16* __restrict__ t1,
                                                         u16* __restrict__ t2, u16* __restrict__ t3,
                                                         u16* __restrict__ t4, u16* __restrict__ t5){
  int b = blockIdx.x;
  if (b < 128){        int idx=(b-0)*256+threadIdx.x;    t0[idx]=f2b(w0[(idx%256)*128  + idx/256]); }
  else if (b < 160){   int idx=(b-128)*256+threadIdx.x;  t1[idx]=f2b(w1[(idx%128)*64   + idx/128]); }
  else if (b < 416){   int idx=(b-160)*256+threadIdx.x;  t2[idx]=f2b(w2[(idx%64)*1024  + idx/64]);  }
  else if (b < 928){   int idx=(b-416)*256+threadIdx.x;  t3[idx]=f2b(w3[(idx%256)*512  + idx/256]); }
  else if (b < 1440){  int idx=(b-928)*256+threadIdx.x;  t4[idx]=f2b(w4[(idx%512)*256  + idx/512]); }
  else {               int idx=(b-1440)*256+threadIdx.x; t5[idx]=f2b(w5[(idx%256)*32   + idx/256]); }
}

// ---------------- gather: e[b, f*16+d] = emb[f, ids[b,f], d] (f32 -> bf16) ----------------
__global__ __launch_bounds__(256) void gather_kernel(const int* __restrict__ ids,
                                                     const float* __restrict__ emb,
                                                     u16* __restrict__ e){
  int b = blockIdx.x; int tid = threadIdx.x;
  int f = tid >> 4, d = tid & 15;
  int id = ids[b*16 + f];
  e[(size_t)b*256 + tid] = f2b(emb[((size_t)f*100000 + (size_t)id)*16 + d]);
}

// ---------------- MFMA GEMM: C = relu(BN(A)) @ W + bias, fused col-stats -----------
// A: bf16 [M][K] ws. Wt: bf16 [N][K] (pre-transposed). bias f32 (nullable).
// ascale/ashift: BN on A (nullable = identity, no relu). sums/sumsq: stats (nullable).
// Tile 64x64, BK=32, 4 waves; wave w covers cols [w*16,w*16+16), 4 MFMAs (M-chunks).
#define ASTR 40
__global__ __launch_bounds__(256) void gemm_mfma(const u16* __restrict__ A,
                                                 const u16* __restrict__ Wt,
                                                 const float* __restrict__ bias,
                                                 u16* __restrict__ C,
                                                 const float* __restrict__ ascale,
                                                 const float* __restrict__ ashift,
                                                 float* __restrict__ sums,
                                                 float* __restrict__ sumsq,
                                                 int N, int K){
  __shared__ u16 lds[64*ASTR*2];
  u16* As = lds;
  u16* Bs = lds + 64*ASTR;
  int tid = threadIdx.x;
  int n0 = blockIdx.x*64, m0 = blockIdx.y*64;
  int srow = tid >> 2, skoff = (tid & 3)*8;
  int lane = tid & 63, w = tid >> 6, quad = lane >> 4, m16 = lane & 15;
  f32x4 acc[4] = {};
  int ng = n0 + srow;
  for (int k0 = 0; k0 < K; k0 += 32){
    // stage A (with optional BN+ReLU)
    uint4 av = *(const uint4*)(A + (size_t)(m0+srow)*K + k0 + skoff);
    u16 at[8]; __builtin_memcpy(at, &av, 16);
    if (ascale != nullptr){
#pragma unroll
      for (int j=0;j<8;j++){
        float v = b2f(at[j]) * ascale[k0+skoff+j] + ashift[k0+skoff+j];
        at[j] = f2b(v > 0.f ? v : 0.f);
      }
    }
    __builtin_memcpy(&av, at, 16);
    *(uint4*)&As[srow*ASTR + skoff] = av;
    // stage B from transposed bf16 weights
    uint4 wv = make_uint4(0u,0u,0u,0u);
    if (ng < N) wv = *(const uint4*)(Wt + (size_t)ng*K + k0 + skoff);
    *(uint4*)&Bs[srow*ASTR + skoff] = wv;
    __syncthreads();
    bf16x8 bfrag = *(bf16x8*)&Bs[(w*16 + m16)*ASTR + quad*8];
#pragma unroll
    for (int mc=0;mc<4;mc++){
      bf16x8 afrag = *(bf16x8*)&As[(mc*16 + m16)*ASTR + quad*8];
      acc[mc] = __builtin_amdgcn_mfma_f32_16x16x32_bf16(afrag, bfrag, acc[mc], 0, 0, 0);
    }
    __syncthreads();
  }
  // epilogue: bias, stats, LDS-staged coalesced store
  int cw = n0 + w*16 + m16;
  float bv = (bias != nullptr && cw < N) ? bias[cw] : 0.f;
  float cs = 0.f, cq = 0.f;
  u16* Cs = lds;                       // 64 x 72 u16 = 9216 u16 < 5120*... (64*ASTR*2=5120 u16? no: 64*40*2 = 5120 u16 total)
#pragma unroll
  for (int mc=0;mc<4;mc++)
#pragma unroll
    for (int r=0;r<4;r++){
      float v = acc[mc][r] + bv;
      cs += v; cq += v*v;
      Cs[(mc*16 + quad*4 + r)*72 + w*16 + m16] = f2b(v);
    }
  if (sums != nullptr){
    cs += __shfl_xor(cs, 16, 64); cs += __shfl_xor(cs, 32, 64);
    cq += __shfl_xor(cq, 16, 64); cq += __shfl_xor(cq, 32, 64);
    if (quad == 0 && cw < N){ atomicAdd(&sums[cw], cs); atomicAdd(&sumsq[cw], cq); }
  }
  __syncthreads();
  int row = tid >> 2, c4 = (tid & 3)*16;
  int cg = n0 + c4;
  if (cg < N){
    uint4 p0 = *(uint4*)&Cs[row*72 + c4];
    uint4 p1 = *(uint4*)&Cs[row*72 + c4 + 8];
    *(uint4*)(C + (size_t)(m0+row)*N + cg) = p0;
    *(uint4*)(C + (size_t)(m0+row)*N + cg + 8) = p1;
  }
}

// ---------------- finalize: biased batch stats -> scale/shift ----------------
__global__ void finalize_kernel(const float* __restrict__ sums, const float* __restrict__ sumsq,
                                const float* __restrict__ g, const float* __restrict__ be,
                                float* __restrict__ scale, float* __restrict__ shift, int N){
  int c = blockIdx.x*256 + threadIdx.x;
  if (c >= N) return;
  float mean = sums[c] / (float)BATCH;
  float var  = sumsq[c] / (float)BATCH - mean*mean;
  float sc = g[c] * rsqrtf(var + 1e-5f);
  scale[c] = sc;
  shift[c] = be[c] - mean * sc;
}

// ---------------- finalize for T: 8 staged copies, unbiased variance ----------------
__global__ void finalizeT_kernel(const float* __restrict__ tpart,
                                 const float* __restrict__ g, const float* __restrict__ be,
                                 float* __restrict__ scale, float* __restrict__ shift){
  int c = threadIdx.x;  // 256
  float s = 0.f, q = 0.f;
#pragma unroll
  for (int k=0;k<8;k++){ s += tpart[k*512 + c]; q += tpart[k*512 + c + 256]; }
  float mean = s / (float)BATCH;
  float var  = (q - mean*mean*(float)BATCH) / (float)(BATCH-1);
  float sc = g[c] * rsqrtf(var + 1e-5f);
  scale[c] = sc;
  shift[c] = be[c] - mean * sc;
}

// ---------------- cross network: 3 iters of x = e*(x.cw)+cb+x ----------------
__global__ __launch_bounds__(256) void cross_kernel(const u16* __restrict__ e,
                                                    const float* __restrict__ cw,
                                                    const float* __restrict__ cb,
                                                    u16* __restrict__ cn){
  __shared__ float red[4];
  int b = blockIdx.x, c = threadIdx.x;
  float ec = b2f(e[(size_t)b*256 + c]);
  float x = ec;
  for (int i=0;i<3;i++){
    float p = x * cw[i*256 + c];
#pragma unroll
    for (int o=32;o>0;o>>=1) p += __shfl_down(p, o, 64);
    if ((c & 63) == 0) red[c>>6] = p;
    __syncthreads();
    float dot = red[0] + red[1] + red[2] + red[3];
    __syncthreads();
    x = ec*dot + cb[i*256 + c] + x;
  }
  cn[(size_t)b*256 + c] = f2b(x);
}

// ---------------- fused adapter: BN(H) on load, low-rank path, T-stats epilogue --------
__global__ __launch_bounds__(256) void adapter_kernel(const u16* __restrict__ H,
                                                      const u16* __restrict__ P,
                                                      const float* __restrict__ v0,
                                                      const float* __restrict__ u1,
                                                      const float* __restrict__ v1,
                                                      const float* __restrict__ ab0,
                                                      const float* __restrict__ ab1,
                                                      const float* __restrict__ hscale,
                                                      const float* __restrict__ hshift,
                                                      float* __restrict__ tpart,
                                                      u16* __restrict__ T){
  __shared__ __align__(16) u16 Hs[8*1024];   // reused as f32 tpart scratch (16KB)
  __shared__ u16 v1b[32*256];
  __shared__ float v0s[32*32];
  __shared__ float u1s[32*32];
  __shared__ float Ps[256], qs[256], t1s[256], ss[256], z2s[256];
  __shared__ float ab0s[32];
  __shared__ float ab1s[256];
  int tid = threadIdx.x;
  int r = tid >> 5, j = tid & 31;
  size_t row0 = (size_t)blockIdx.x * 8;

  for (int k = tid; k < 8*1024; k += 256){
    int col = k & 1023;
    float v = b2f(H[row0*1024 + k]) * hscale[col] + hshift[col];
    Hs[k] = f2b(v > 0.f ? v : 0.f);
  }
  for (int k = tid; k < 1024; k += 256){ v0s[k] = v0[k]; u1s[k] = u1[k]; }
  for (int k = tid; k < 32*256; k += 256) v1b[k] = f2b(v1[k]);
  if (tid < 32) ab0s[tid] = ab0[tid];
  ab1s[tid] = ab1[tid];
  Ps[tid] = b2f(P[row0*32 + tid]);
  __syncthreads();

  float acc = 0.f;
#pragma unroll
  for (int i=0;i<32;i++) acc += Ps[r*32+i] * b2f(Hs[r*1024 + i*32 + j]);
  qs[r*32+j] = acc;
  __syncthreads();

  acc = ab0s[j];
#pragma unroll
  for (int i=0;i<32;i++) acc += qs[r*32+i] * v0s[i*32+j];
  t1s[r*32+j] = 1.f / (1.f + __expf(-acc));
  __syncthreads();

  acc = 0.f;
#pragma unroll
  for (int i=0;i<32;i++) acc += t1s[r*32+i] * u1s[i*32+j];
  ss[r*32+j] = acc;
  __syncthreads();

  acc = 0.f;
#pragma unroll
  for (int i=0;i<32;i++) acc += ss[r*32+i] * b2f(Hs[r*1024 + i*32 + j]);
  z2s[r*32+j] = acc;
  __syncthreads();          // Hs dead; reuse for T partials

  float* tp = (float*)Hs;
  float* tq = tp + 2048;
  for (int n = j; n < 256; n += 32){
    float a2 = ab1s[n];
#pragma unroll
    for (int i=0;i<32;i++) a2 += z2s[r*32+i] * b2f(v1b[i*256 + n]);
    T[(row0 + r)*256 + n] = f2b(a2);
    tp[r*256 + n] = a2;
    tq[r*256 + n] = a2*a2;
  }
  __syncthreads();
  {
    int c = tid;
    float s8 = 0.f, q8 = 0.f;
#pragma unroll
    for (int rr=0;rr<8;rr++){ s8 += tp[rr*256 + c]; q8 += tq[rr*256 + c]; }
    float* dst = tpart + (size_t)(blockIdx.x & 7) * 512;
    atomicAdd(&dst[c], s8);
    atomicAdd(&dst[c + 256], q8);
  }
}

// ---------------- final head ----------------
__global__ __launch_bounds__(256) void final_kernel(const u16* __restrict__ cn,
                                                    const u16* __restrict__ t,
                                                    const u16* __restrict__ mo,
                                                    const float* __restrict__ tS,
                                                    const float* __restrict__ tB,
                                                    const float* __restrict__ mS,
                                                    const float* __restrict__ mB,
                                                    const float* __restrict__ lw,
                                                    const float* __restrict__ lb,
                                                    float* __restrict__ out){
  int wave = threadIdx.x >> 6, lane = threadIdx.x & 63;
  int b = blockIdx.x*4 + wave;
  float p = 0.f;
  for (int n = lane; n < 256; n += 64){
    p += b2f(cn[(size_t)b*256 + n]) * lw[n];
    float mr = b2f(mo[(size_t)b*256 + n]) * mS[n] + mB[n];
    mr = mr > 0.f ? mr : 0.f;
    float mf = tS[n]*b2f(t[(size_t)b*256 + n]) + tB[n] + mr;
    p += mf * lw[256 + n];
  }
#pragma unroll
  for (int o=32;o>0;o>>=1) p += __shfl_down(p, o, 64);
  if (lane == 0){
    float y = p + lb[0];
    out[b] = 1.f / (1.f + __expf(-y));
  }
}

extern "C" void kernel_launch(void* const* d_in, const int* in_sizes, int n_in,
                              void* d_out, int out_size, void* d_ws, size_t ws_size,
                              hipStream_t stream) {
  const int B = BATCH;
  const int*   feat = (const int*)d_in[0];
  const float* emb  = (const float*)d_in[2];
  const float* hW0 = (const float*)d_in[3],  *hb0 = (const float*)d_in[4],  *hg0 = (const float*)d_in[5],  *hbe0 = (const float*)d_in[6];
  const float* hW1 = (const float*)d_in[7],  *hb1 = (const float*)d_in[8],  *hg1 = (const float*)d_in[9],  *hbe1 = (const float*)d_in[10];
  const float* hW2 = (const float*)d_in[11], *hb2 = (const float*)d_in[12], *hg2 = (const float*)d_in[13], *hbe2 = (const float*)d_in[14];
  const float* cw  = (const float*)d_in[15], *cb  = (const float*)d_in[16];
  const float* mW0 = (const float*)d_in[17], *mb0 = (const float*)d_in[18], *mg0 = (const float*)d_in[19], *mbe0 = (const float*)d_in[20];
  const float* mW1 = (const float*)d_in[21], *mb1 = (const float*)d_in[22], *mg1 = (const float*)d_in[23], *mbe1 = (const float*)d_in[24];
  const float* u0  = (const float*)d_in[25], *u1  = (const float*)d_in[26];
  const float* v0  = (const float*)d_in[27], *v1  = (const float*)d_in[28];
  const float* ab0 = (const float*)d_in[29], *ab1 = (const float*)d_in[30];
  const float* gamma1 = (const float*)d_in[31], *bias1 = (const float*)d_in[32];
  const float* lw  = (const float*)d_in[33], *lb = (const float*)d_in[34];
  float* out = (float*)d_out;

  // ---- aliased workspace (64 MB + 384 KB) ----
  // [ 0M,32M): H (raw)
  // [32M,40M): e -> T
  // [40M,56M): Y0[0,4M)+Y1[4M,6M) -> M0 -> cn[0,8M)+P[8M,9M)
  // [56M,64M): {hW0t,hW1t,hW2t,mW0t} (dead before Mout gemm) -> Mout
  // [64M,64M+104K): stats | [64M+112K, +384K): mW1t, u0t
  char* base = (char*)d_ws;
  const size_t MB = 1024*1024;
  u16* H    = (u16*)(base);
  u16* e    = (u16*)(base + 32*MB);
  u16* T    = (u16*)(base + 32*MB);
  u16* Y0   = (u16*)(base + 40*MB);
  u16* Y1   = (u16*)(base + 44*MB);
  u16* M0   = (u16*)(base + 40*MB);
  u16* cn   = (u16*)(base + 40*MB);
  u16* P    = (u16*)(base + 48*MB);
  u16* Mout = (u16*)(base + 56*MB);
  u16* hW0t = (u16*)(base + 56*MB);          // 32768 el
  u16* hW1t = hW0t + 32768;                  // 8192
  u16* hW2t = hW1t + 8192;                   // 65536
  u16* mW0t = hW2t + 65536;                  // 131072  (ends ~464 KB into Mout region)
  float* S  = (float*)(base + 64*MB);
  auto sums  = [&](int l){ return S + l*2048; };
  auto sumsq = [&](int l){ return S + l*2048 + 1024; };
  float* tpart = S + 10240;                  // 8 x [256|256]
  float* SS = S + 14336;
  auto scl = [&](int l){ return SS + l*2048; };
  auto shf = [&](int l){ return SS + l*2048 + 1024; };
  u16* mW1t = (u16*)(base + 64*MB + 112*1024);   // 131072 el (survives Mout gemm)
  u16* u0t  = mW1t + 131072;                 // 8192 el

  // zero stats accumulators (sums + tpart)
  zero_kernel<<<56, 256, 0, stream>>>(S, 14336);
  // transpose+convert all weights to bf16 [N][K]
  transpose_weights<<<1472, 256, 0, stream>>>(hW0, hW1, hW2, mW0, mW1, u0,
                                              hW0t, hW1t, hW2t, mW0t, mW1t, u0t);
  // gather
  gather_kernel<<<B, 256, 0, stream>>>(feat, emb, e);

  // hyper chain -> H
  gemm_mfma<<<dim3(2, B/64), 256, 0, stream>>>(e,  hW0t, hb0, Y0, nullptr, nullptr, sums(0), sumsq(0), 128, 256);
  finalize_kernel<<<1, 256, 0, stream>>>(sums(0), sumsq(0), hg0, hbe0, scl(0), shf(0), 128);

  gemm_mfma<<<dim3(1, B/64), 256, 0, stream>>>(Y0, hW1t, hb1, Y1, scl(0), shf(0), sums(1), sumsq(1), 64, 128);
  finalize_kernel<<<1, 256, 0, stream>>>(sums(1), sumsq(1), hg1, hbe1, scl(1), shf(1), 64);

  gemm_mfma<<<dim3(16, B/64), 256, 0, stream>>>(Y1, hW2t, hb2, H, scl(1), shf(1), sums(2), sumsq(2), 1024, 64);
  finalize_kernel<<<4, 256, 0, stream>>>(sums(2), sumsq(2), hg2, hbe2, scl(2), shf(2), 1024);

  // MLP chain
  gemm_mfma<<<dim3(8, B/64), 256, 0, stream>>>(e,  mW0t, mb0, M0, nullptr, nullptr, sums(3), sumsq(3), 512, 256);
  finalize_kernel<<<2, 256, 0, stream>>>(sums(3), sumsq(3), mg0, mbe0, scl(3), shf(3), 512);

  gemm_mfma<<<dim3(4, B/64), 256, 0, stream>>>(M0, mW1t, mb1, Mout, scl(3), shf(3), sums(4), sumsq(4), 256, 512);
  finalize_kernel<<<1, 256, 0, stream>>>(sums(4), sumsq(4), mg1, mbe1, scl(4), shf(4), 256);

  // cross network
  cross_kernel<<<B, 256, 0, stream>>>(e, cw, cb, cn);

  // adapter: P = BN_relu(Mout)@u0, then fused low-rank path
  gemm_mfma<<<dim3(1, B/64), 256, 0, stream>>>(Mout, u0t, nullptr, P, scl(4), shf(4), nullptr, nullptr, 32, 256);
  adapter_kernel<<<B/8, 256, 0, stream>>>(H, P, v0, u1, v1, ab0, ab1, scl(2), shf(2), tpart, T);

  // unbiased BN stats for T, then final head
  finalizeT_kernel<<<1, 256, 0, stream>>>(tpart, gamma1, bias1, scl(5), shf(5));
  final_kernel<<<B/4, 256, 0, stream>>>(cn, T, Mout, scl(5), shf(5), scl(4), shf(4), lw, lb, out);
}

// Round 6
// 371.214 us; speedup vs baseline: 2.1080x; 1.1038x over previous
//
#include <hip/hip_runtime.h>

typedef unsigned short u16;
typedef __attribute__((ext_vector_type(8))) short bf16x8;
typedef __attribute__((ext_vector_type(4))) float f32x4;
#define BATCH 16384

__device__ __forceinline__ float b2f(u16 u){ unsigned int i=((unsigned int)u)<<16; float f; __builtin_memcpy(&f,&i,4); return f; }
__device__ __forceinline__ u16 f2b(float f){ unsigned int x; __builtin_memcpy(&x,&f,4); unsigned int r=(x + 0x7fffu + ((x>>16)&1u))>>16; return (u16)r; }

// ---------------- zero fp32 buffer (graph-capture-safe memset) ----------------
__global__ __launch_bounds__(256) void zero_kernel(float* __restrict__ p, int n){
  int i = blockIdx.x*256 + threadIdx.x;
  if (i < n) p[i] = 0.f;
}

// ---------------- one-shot: transpose+convert weights to bf16 [N][K] ----------------
__global__ __launch_bounds__(256) void transpose_weights(const float* __restrict__ w0, const float* __restrict__ w1,
                                                         const float* __restrict__ w2, const float* __restrict__ w3,
                                                         const float* __restrict__ w4, const float* __restrict__ w5,
                                                         const float* __restrict__ w6,
                                                         u16* __restrict__ t0, u16* __restrict__ t1,
                                                         u16* __restrict__ t2, u16* __restrict__ t3,
                                                         u16* __restrict__ t4, u16* __restrict__ t5,
                                                         u16* __restrict__ t6){
  int b = blockIdx.x;
  if (b < 128){        int idx=(b-0)*256+threadIdx.x;    t0[idx]=f2b(w0[(idx%256)*128  + idx/256]); }
  else if (b < 160){   int idx=(b-128)*256+threadIdx.x;  t1[idx]=f2b(w1[(idx%128)*64   + idx/128]); }
  else if (b < 416){   int idx=(b-160)*256+threadIdx.x;  t2[idx]=f2b(w2[(idx%64)*1024  + idx/64]);  }
  else if (b < 928){   int idx=(b-416)*256+threadIdx.x;  t3[idx]=f2b(w3[(idx%256)*512  + idx/256]); }
  else if (b < 1440){  int idx=(b-928)*256+threadIdx.x;  t4[idx]=f2b(w4[(idx%512)*256  + idx/512]); }
  else if (b < 1472){  int idx=(b-1440)*256+threadIdx.x; t5[idx]=f2b(w5[(idx%256)*32   + idx/256]); }
  else {               int idx=(b-1472)*256+threadIdx.x; t6[idx]=f2b(w6[(idx%32)*256   + idx/32]);  }
}

// ---------------- gather: e[b, f*16+d] = emb[f, ids[b,f], d] (f32 -> bf16) ----------------
__global__ __launch_bounds__(256) void gather_kernel(const int* __restrict__ ids,
                                                     const float* __restrict__ emb,
                                                     u16* __restrict__ e){
  int b = blockIdx.x; int tid = threadIdx.x;
  int f = tid >> 4, d = tid & 15;
  int id = ids[b*16 + f];
  e[(size_t)b*256 + tid] = f2b(emb[((size_t)f*100000 + (size_t)id)*16 + d]);
}

// ---------------- MFMA GEMM: C = relu(BN(A)) @ W + bias, fused col-stats -----------
// Tile 64x64, BK=32, 4 waves; wave w covers cols [w*16,w*16+16), 4 MFMAs (M-chunks).
#define ASTR 40
__global__ __launch_bounds__(256) void gemm_mfma(const u16* __restrict__ A,
                                                 const u16* __restrict__ Wt,
                                                 const float* __restrict__ bias,
                                                 u16* __restrict__ C,
                                                 const float* __restrict__ ascale,
                                                 const float* __restrict__ ashift,
                                                 float* __restrict__ sums,
                                                 float* __restrict__ sumsq,
                                                 int N, int K){
  __shared__ u16 lds[64*ASTR*2];
  u16* As = lds;
  u16* Bs = lds + 64*ASTR;
  int tid = threadIdx.x;
  int n0 = blockIdx.x*64, m0 = blockIdx.y*64;
  int srow = tid >> 2, skoff = (tid & 3)*8;
  int lane = tid & 63, w = tid >> 6, quad = lane >> 4, m16 = lane & 15;
  f32x4 acc[4] = {};
  int ng = n0 + srow;
  for (int k0 = 0; k0 < K; k0 += 32){
    uint4 av = *(const uint4*)(A + (size_t)(m0+srow)*K + k0 + skoff);
    u16 at[8]; __builtin_memcpy(at, &av, 16);
    if (ascale != nullptr){
#pragma unroll
      for (int j=0;j<8;j++){
        float v = b2f(at[j]) * ascale[k0+skoff+j] + ashift[k0+skoff+j];
        at[j] = f2b(v > 0.f ? v : 0.f);
      }
    }
    __builtin_memcpy(&av, at, 16);
    *(uint4*)&As[srow*ASTR + skoff] = av;
    uint4 wv = make_uint4(0u,0u,0u,0u);
    if (ng < N) wv = *(const uint4*)(Wt + (size_t)ng*K + k0 + skoff);
    *(uint4*)&Bs[srow*ASTR + skoff] = wv;
    __syncthreads();
    bf16x8 bfrag = *(bf16x8*)&Bs[(w*16 + m16)*ASTR + quad*8];
#pragma unroll
    for (int mc=0;mc<4;mc++){
      bf16x8 afrag = *(bf16x8*)&As[(mc*16 + m16)*ASTR + quad*8];
      acc[mc] = __builtin_amdgcn_mfma_f32_16x16x32_bf16(afrag, bfrag, acc[mc], 0, 0, 0);
    }
    __syncthreads();
  }
  int cw = n0 + w*16 + m16;
  float bv = (bias != nullptr && cw < N) ? bias[cw] : 0.f;
  float cs = 0.f, cq = 0.f;
  u16* Cs = lds;
#pragma unroll
  for (int mc=0;mc<4;mc++)
#pragma unroll
    for (int r=0;r<4;r++){
      float v = acc[mc][r] + bv;
      cs += v; cq += v*v;
      Cs[(mc*16 + quad*4 + r)*72 + w*16 + m16] = f2b(v);
    }
  if (sums != nullptr){
    cs += __shfl_xor(cs, 16, 64); cs += __shfl_xor(cs, 32, 64);
    cq += __shfl_xor(cq, 16, 64); cq += __shfl_xor(cq, 32, 64);
    if (quad == 0 && cw < N){ atomicAdd(&sums[cw], cs); atomicAdd(&sumsq[cw], cq); }
  }
  __syncthreads();
  int row = tid >> 2, c4 = (tid & 3)*16;
  int cg = n0 + c4;
  if (cg < N){
    uint4 p0 = *(uint4*)&Cs[row*72 + c4];
    uint4 p1 = *(uint4*)&Cs[row*72 + c4 + 8];
    *(uint4*)(C + (size_t)(m0+row)*N + cg) = p0;
    *(uint4*)(C + (size_t)(m0+row)*N + cg + 8) = p1;
  }
}

// ---------------- finalize: batch stats -> scale/shift (biased or unbiased) ----------------
__global__ void finalize_kernel(const float* __restrict__ sums, const float* __restrict__ sumsq,
                                const float* __restrict__ g, const float* __restrict__ be,
                                float* __restrict__ scale, float* __restrict__ shift,
                                int N, int unbiased){
  int c = blockIdx.x*256 + threadIdx.x;
  if (c >= N) return;
  float mean = sums[c] / (float)BATCH;
  float var;
  if (unbiased) var = (sumsq[c] - mean*mean*(float)BATCH) / (float)(BATCH-1);
  else          var = sumsq[c] / (float)BATCH - mean*mean;
  float sc = g[c] * rsqrtf(var + 1e-5f);
  scale[c] = sc;
  shift[c] = be[c] - mean * sc;
}

// ---------------- adapter core: BN(H) on load, q->t1->s->z2, write Z2[B,32] ----------------
__global__ __launch_bounds__(256) void adapter_core(const u16* __restrict__ H,
                                                    const u16* __restrict__ P,
                                                    const float* __restrict__ v0,
                                                    const float* __restrict__ u1,
                                                    const float* __restrict__ ab0,
                                                    const float* __restrict__ hscale,
                                                    const float* __restrict__ hshift,
                                                    u16* __restrict__ Z2){
  __shared__ __align__(16) u16 Hs[8*1024];
  __shared__ float v0s[1024], u1s[1024];
  __shared__ float Ps[256], qs[256], t1s[256], ss[256];
  __shared__ float ab0s[32];
  int tid = threadIdx.x;
  int r = tid >> 5, j = tid & 31;
  size_t row0 = (size_t)blockIdx.x * 8;

  for (int k = tid; k < 8*1024; k += 256){
    int col = k & 1023;
    float v = b2f(H[row0*1024 + k]) * hscale[col] + hshift[col];
    Hs[k] = f2b(v > 0.f ? v : 0.f);
  }
  for (int k = tid; k < 1024; k += 256){ v0s[k] = v0[k]; u1s[k] = u1[k]; }
  if (tid < 32) ab0s[tid] = ab0[tid];
  Ps[tid] = b2f(P[row0*32 + tid]);
  __syncthreads();

  float acc = 0.f;
#pragma unroll
  for (int i=0;i<32;i++) acc += Ps[r*32+i] * b2f(Hs[r*1024 + i*32 + j]);
  qs[r*32+j] = acc;
  __syncthreads();

  acc = ab0s[j];
#pragma unroll
  for (int i=0;i<32;i++) acc += qs[r*32+i] * v0s[i*32+j];
  t1s[r*32+j] = 1.f / (1.f + __expf(-acc));
  __syncthreads();

  acc = 0.f;
#pragma unroll
  for (int i=0;i<32;i++) acc += t1s[r*32+i] * u1s[i*32+j];
  ss[r*32+j] = acc;
  __syncthreads();

  acc = 0.f;
#pragma unroll
  for (int i=0;i<32;i++) acc += ss[r*32+i] * b2f(Hs[r*1024 + i*32 + j]);
  Z2[(row0 + r)*32 + j] = f2b(acc);
}

// ---------------- final head: cross-net on e + BN(t) + BN/ReLU(Mout) + LR + sigmoid -----
__global__ __launch_bounds__(256) void final_kernel(const u16* __restrict__ e,
                                                    const float* __restrict__ cw,
                                                    const float* __restrict__ cb,
                                                    const u16* __restrict__ t,
                                                    const u16* __restrict__ mo,
                                                    const float* __restrict__ tS,
                                                    const float* __restrict__ tB,
                                                    const float* __restrict__ mS,
                                                    const float* __restrict__ mB,
                                                    const float* __restrict__ lw,
                                                    const float* __restrict__ lb,
                                                    float* __restrict__ out){
  int wave = threadIdx.x >> 6, lane = threadIdx.x & 63;
  int b = blockIdx.x*4 + wave;
  int n4 = lane*4;
  // load 4 bf16 of e
  ushort4 ev = *(const ushort4*)(e + (size_t)b*256 + n4);
  float ec[4] = { b2f(ev.x), b2f(ev.y), b2f(ev.z), b2f(ev.w) };
  float x[4]  = { ec[0], ec[1], ec[2], ec[3] };
  // 3 cross iterations
  for (int i=0;i<3;i++){
    float p = 0.f;
#pragma unroll
    for (int q=0;q<4;q++) p += x[q] * cw[i*256 + n4 + q];
#pragma unroll
    for (int o=1;o<64;o<<=1) p += __shfl_xor(p, o, 64);
#pragma unroll
    for (int q=0;q<4;q++) x[q] = ec[q]*p + cb[i*256 + n4 + q] + x[q];
  }
  // concat-dot with lw
  ushort4 tv = *(const ushort4*)(t  + (size_t)b*256 + n4);
  ushort4 mv = *(const ushort4*)(mo + (size_t)b*256 + n4);
  float ta[4] = { b2f(tv.x), b2f(tv.y), b2f(tv.z), b2f(tv.w) };
  float ma[4] = { b2f(mv.x), b2f(mv.y), b2f(mv.z), b2f(mv.w) };
  float p = 0.f;
#pragma unroll
  for (int q=0;q<4;q++){
    int n = n4 + q;
    p += x[q] * lw[n];
    float mr = ma[q]*mS[n] + mB[n];
    mr = mr > 0.f ? mr : 0.f;
    float mf = tS[n]*ta[q] + tB[n] + mr;
    p += mf * lw[256 + n];
  }
#pragma unroll
  for (int o=32;o>0;o>>=1) p += __shfl_down(p, o, 64);
  if (lane == 0){
    float y = p + lb[0];
    out[b] = 1.f / (1.f + __expf(-y));
  }
}

extern "C" void kernel_launch(void* const* d_in, const int* in_sizes, int n_in,
                              void* d_out, int out_size, void* d_ws, size_t ws_size,
                              hipStream_t stream) {
  const int B = BATCH;
  const int*   feat = (const int*)d_in[0];
  const float* emb  = (const float*)d_in[2];
  const float* hW0 = (const float*)d_in[3],  *hb0 = (const float*)d_in[4],  *hg0 = (const float*)d_in[5],  *hbe0 = (const float*)d_in[6];
  const float* hW1 = (const float*)d_in[7],  *hb1 = (const float*)d_in[8],  *hg1 = (const float*)d_in[9],  *hbe1 = (const float*)d_in[10];
  const float* hW2 = (const float*)d_in[11], *hb2 = (const float*)d_in[12], *hg2 = (const float*)d_in[13], *hbe2 = (const float*)d_in[14];
  const float* cw  = (const float*)d_in[15], *cb  = (const float*)d_in[16];
  const float* mW0 = (const float*)d_in[17], *mb0 = (const float*)d_in[18], *mg0 = (const float*)d_in[19], *mbe0 = (const float*)d_in[20];
  const float* mW1 = (const float*)d_in[21], *mb1 = (const float*)d_in[22], *mg1 = (const float*)d_in[23], *mbe1 = (const float*)d_in[24];
  const float* u0  = (const float*)d_in[25], *u1  = (const float*)d_in[26];
  const float* v0  = (const float*)d_in[27], *v1  = (const float*)d_in[28];
  const float* ab0 = (const float*)d_in[29], *ab1 = (const float*)d_in[30];
  const float* gamma1 = (const float*)d_in[31], *bias1 = (const float*)d_in[32];
  const float* lw  = (const float*)d_in[33], *lb = (const float*)d_in[34];
  float* out = (float*)d_out;

  // ---- aliased workspace (~64.4 MB) ----
  // [ 0M,32M): H (live until adapter_core)
  // [32M,40M): e (live until final)
  // [40M,56M): Y0[40M)+Y1[44M) -> M0 -> T[40M,48M)+P[48M,49M)+Z2[49M,50M)
  // [56M,64M): {hW0t,hW1t,hW2t,mW0t} (dead before Mout gemm) -> Mout
  // [64M,+96K): stats | [64M+112K,+400K): mW1t, u0t, v1t
  char* base = (char*)d_ws;
  const size_t MB = 1024*1024;
  u16* H    = (u16*)(base);
  u16* e    = (u16*)(base + 32*MB);
  u16* Y0   = (u16*)(base + 40*MB);
  u16* Y1   = (u16*)(base + 44*MB);
  u16* M0   = (u16*)(base + 40*MB);
  u16* T    = (u16*)(base + 40*MB);
  u16* P    = (u16*)(base + 48*MB);
  u16* Z2   = (u16*)(base + 49*MB);
  u16* Mout = (u16*)(base + 56*MB);
  u16* hW0t = (u16*)(base + 56*MB);          // 32768 el
  u16* hW1t = hW0t + 32768;                  // 8192
  u16* hW2t = hW1t + 8192;                   // 65536
  u16* mW0t = hW2t + 65536;                  // 131072
  float* S  = (float*)(base + 64*MB);
  auto sums  = [&](int l){ return S + l*2048; };
  auto sumsq = [&](int l){ return S + l*2048 + 1024; };
  float* SS = S + 12288;
  auto scl = [&](int l){ return SS + l*2048; };
  auto shf = [&](int l){ return SS + l*2048 + 1024; };
  u16* mW1t = (u16*)(base + 64*MB + 112*1024);   // 131072 el
  u16* u0t  = mW1t + 131072;                 // 8192
  u16* v1t  = u0t + 8192;                    // 8192

  // zero stats accumulators
  zero_kernel<<<48, 256, 0, stream>>>(S, 12288);
  // transpose+convert all weights to bf16 [N][K]
  transpose_weights<<<1504, 256, 0, stream>>>(hW0, hW1, hW2, mW0, mW1, u0, v1,
                                              hW0t, hW1t, hW2t, mW0t, mW1t, u0t, v1t);
  // gather
  gather_kernel<<<B, 256, 0, stream>>>(feat, emb, e);

  // hyper chain -> H
  gemm_mfma<<<dim3(2, B/64), 256, 0, stream>>>(e,  hW0t, hb0, Y0, nullptr, nullptr, sums(0), sumsq(0), 128, 256);
  finalize_kernel<<<1, 256, 0, stream>>>(sums(0), sumsq(0), hg0, hbe0, scl(0), shf(0), 128, 0);

  gemm_mfma<<<dim3(1, B/64), 256, 0, stream>>>(Y0, hW1t, hb1, Y1, scl(0), shf(0), sums(1), sumsq(1), 64, 128);
  finalize_kernel<<<1, 256, 0, stream>>>(sums(1), sumsq(1), hg1, hbe1, scl(1), shf(1), 64, 0);

  gemm_mfma<<<dim3(16, B/64), 256, 0, stream>>>(Y1, hW2t, hb2, H, scl(1), shf(1), sums(2), sumsq(2), 1024, 64);
  finalize_kernel<<<4, 256, 0, stream>>>(sums(2), sumsq(2), hg2, hbe2, scl(2), shf(2), 1024, 0);

  // MLP chain
  gemm_mfma<<<dim3(8, B/64), 256, 0, stream>>>(e,  mW0t, mb0, M0, nullptr, nullptr, sums(3), sumsq(3), 512, 256);
  finalize_kernel<<<2, 256, 0, stream>>>(sums(3), sumsq(3), mg0, mbe0, scl(3), shf(3), 512, 0);

  gemm_mfma<<<dim3(4, B/64), 256, 0, stream>>>(M0, mW1t, mb1, Mout, scl(3), shf(3), sums(4), sumsq(4), 256, 512);
  finalize_kernel<<<1, 256, 0, stream>>>(sums(4), sumsq(4), mg1, mbe1, scl(4), shf(4), 256, 0);

  // adapter: P = BN_relu(Mout)@u0 ; core -> Z2 ; T = Z2@v1t + ab1 (stats fused)
  gemm_mfma<<<dim3(1, B/64), 256, 0, stream>>>(Mout, u0t, nullptr, P, scl(4), shf(4), nullptr, nullptr, 32, 256);
  adapter_core<<<B/8, 256, 0, stream>>>(H, P, v0, u1, ab0, scl(2), shf(2), Z2);
  gemm_mfma<<<dim3(4, B/64), 256, 0, stream>>>(Z2, v1t, ab1, T, nullptr, nullptr, sums(5), sumsq(5), 256, 32);
  finalize_kernel<<<1, 256, 0, stream>>>(sums(5), sumsq(5), gamma1, bias1, scl(5), shf(5), 256, 1);

  // final head (cross fused in)
  final_kernel<<<B/4, 256, 0, stream>>>(e, cw, cb, T, Mout, scl(5), shf(5), scl(4), shf(4), lw, lb, out);
}

// Round 7
// 357.081 us; speedup vs baseline: 2.1914x; 1.0396x over previous
//
#include <hip/hip_runtime.h>

typedef unsigned short u16;
typedef __attribute__((ext_vector_type(8))) short bf16x8;
typedef __attribute__((ext_vector_type(4))) float f32x4;
#define BATCH 16384

__device__ __forceinline__ float b2f(u16 u){ unsigned int i=((unsigned int)u)<<16; float f; __builtin_memcpy(&f,&i,4); return f; }
__device__ __forceinline__ u16 f2b(float f){ unsigned int x; __builtin_memcpy(&x,&f,4); unsigned int r=(x + 0x7fffu + ((x>>16)&1u))>>16; return (u16)r; }

// ---------------- prep: zero stats + transpose weights + gather, one launch ----------------
// blocks [0,48): zero S[12288]
// blocks [48,1552): transpose+convert 7 weight matrices to bf16 [N][K]
// blocks [1552,17936): gather e
__global__ __launch_bounds__(256) void prep_kernel(float* __restrict__ S,
                                                   const float* __restrict__ w0, const float* __restrict__ w1,
                                                   const float* __restrict__ w2, const float* __restrict__ w3,
                                                   const float* __restrict__ w4, const float* __restrict__ w5,
                                                   const float* __restrict__ w6,
                                                   u16* __restrict__ t0, u16* __restrict__ t1,
                                                   u16* __restrict__ t2, u16* __restrict__ t3,
                                                   u16* __restrict__ t4, u16* __restrict__ t5,
                                                   u16* __restrict__ t6,
                                                   const int* __restrict__ ids,
                                                   const float* __restrict__ emb,
                                                   u16* __restrict__ e){
  int blk = blockIdx.x;
  if (blk < 48){
    int i = blk*256 + threadIdx.x;
    if (i < 12288) S[i] = 0.f;
  } else if (blk < 1552){
    int b = blk - 48;
    if (b < 128){        int idx=(b-0)*256+threadIdx.x;    t0[idx]=f2b(w0[(idx%256)*128  + idx/256]); }
    else if (b < 160){   int idx=(b-128)*256+threadIdx.x;  t1[idx]=f2b(w1[(idx%128)*64   + idx/128]); }
    else if (b < 416){   int idx=(b-160)*256+threadIdx.x;  t2[idx]=f2b(w2[(idx%64)*1024  + idx/64]);  }
    else if (b < 928){   int idx=(b-416)*256+threadIdx.x;  t3[idx]=f2b(w3[(idx%256)*512  + idx/256]); }
    else if (b < 1440){  int idx=(b-928)*256+threadIdx.x;  t4[idx]=f2b(w4[(idx%512)*256  + idx/512]); }
    else if (b < 1472){  int idx=(b-1440)*256+threadIdx.x; t5[idx]=f2b(w5[(idx%256)*32   + idx/256]); }
    else {               int idx=(b-1472)*256+threadIdx.x; t6[idx]=f2b(w6[(idx%32)*256   + idx/32]);  }
  } else {
    int b = blk - 1552;
    int tid = threadIdx.x;
    int f = tid >> 4, d = tid & 15;
    int id = ids[b*16 + f];
    e[(size_t)b*256 + tid] = f2b(emb[((size_t)f*100000 + (size_t)id)*16 + d]);
  }
}

// ---------------- MFMA GEMM: C = relu(BN(A)) @ W + bias, inline BN table, fused col-stats --
// BN on A computed from raw batch stats (asums/asumsq) + g/be; nullptr = identity (no relu).
// Tile 64x64, BK=32, 4 waves; wave w covers cols [w*16,w*16+16), 4 MFMAs (M-chunks).
#define ASTR 40
__global__ __launch_bounds__(256) void gemm_mfma(const u16* __restrict__ A,
                                                 const u16* __restrict__ Wt,
                                                 const float* __restrict__ bias,
                                                 u16* __restrict__ C,
                                                 const float* __restrict__ asums,
                                                 const float* __restrict__ asumsq,
                                                 const float* __restrict__ ag,
                                                 const float* __restrict__ abe,
                                                 float* __restrict__ sums,
                                                 float* __restrict__ sumsq,
                                                 int N, int K){
  __shared__ u16 lds[64*ASTR*2];
  __shared__ float bnS[512], bnB[512];
  u16* As = lds;
  u16* Bs = lds + 64*ASTR;
  int tid = threadIdx.x;
  int n0 = blockIdx.x*64, m0 = blockIdx.y*64;
  int srow = tid >> 2, skoff = (tid & 3)*8;
  int lane = tid & 63, w = tid >> 6, quad = lane >> 4, m16 = lane & 15;
  if (asums != nullptr){
    for (int k = tid; k < K; k += 256){
      float mean = asums[k] * (1.f/(float)BATCH);
      float var  = asumsq[k] * (1.f/(float)BATCH) - mean*mean;
      float sc   = ag[k] * rsqrtf(var + 1e-5f);
      bnS[k] = sc;
      bnB[k] = abe[k] - mean*sc;
    }
    __syncthreads();
  }
  f32x4 acc[4] = {};
  int ng = n0 + srow;
  for (int k0 = 0; k0 < K; k0 += 32){
    uint4 av = *(const uint4*)(A + (size_t)(m0+srow)*K + k0 + skoff);
    u16 at[8]; __builtin_memcpy(at, &av, 16);
    if (asums != nullptr){
#pragma unroll
      for (int j=0;j<8;j++){
        float v = b2f(at[j]) * bnS[k0+skoff+j] + bnB[k0+skoff+j];
        at[j] = f2b(v > 0.f ? v : 0.f);
      }
    }
    __builtin_memcpy(&av, at, 16);
    *(uint4*)&As[srow*ASTR + skoff] = av;
    uint4 wv = make_uint4(0u,0u,0u,0u);
    if (ng < N) wv = *(const uint4*)(Wt + (size_t)ng*K + k0 + skoff);
    *(uint4*)&Bs[srow*ASTR + skoff] = wv;
    __syncthreads();
    bf16x8 bfrag = *(bf16x8*)&Bs[(w*16 + m16)*ASTR + quad*8];
#pragma unroll
    for (int mc=0;mc<4;mc++){
      bf16x8 afrag = *(bf16x8*)&As[(mc*16 + m16)*ASTR + quad*8];
      acc[mc] = __builtin_amdgcn_mfma_f32_16x16x32_bf16(afrag, bfrag, acc[mc], 0, 0, 0);
    }
    __syncthreads();
  }
  int cw = n0 + w*16 + m16;
  float bv = (bias != nullptr && cw < N) ? bias[cw] : 0.f;
  float cs = 0.f, cq = 0.f;
  u16* Cs = lds;
#pragma unroll
  for (int mc=0;mc<4;mc++)
#pragma unroll
    for (int r=0;r<4;r++){
      float v = acc[mc][r] + bv;
      cs += v; cq += v*v;
      Cs[(mc*16 + quad*4 + r)*72 + w*16 + m16] = f2b(v);
    }
  if (sums != nullptr){
    cs += __shfl_xor(cs, 16, 64); cs += __shfl_xor(cs, 32, 64);
    cq += __shfl_xor(cq, 16, 64); cq += __shfl_xor(cq, 32, 64);
    if (quad == 0 && cw < N){ atomicAdd(&sums[cw], cs); atomicAdd(&sumsq[cw], cq); }
  }
  __syncthreads();
  int row = tid >> 2, c4 = (tid & 3)*16;
  int cg = n0 + c4;
  if (cg < N){
    uint4 p0 = *(uint4*)&Cs[row*72 + c4];
    uint4 p1 = *(uint4*)&Cs[row*72 + c4 + 8];
    *(uint4*)(C + (size_t)(m0+row)*N + cg) = p0;
    *(uint4*)(C + (size_t)(m0+row)*N + cg + 8) = p1;
  }
}

// ---------------- adapter core: inline BN(H) table, q->t1->s->z2, write Z2[B,32] ----------
__global__ __launch_bounds__(256) void adapter_core(const u16* __restrict__ H,
                                                    const u16* __restrict__ P,
                                                    const float* __restrict__ v0,
                                                    const float* __restrict__ u1,
                                                    const float* __restrict__ ab0,
                                                    const float* __restrict__ hsums,
                                                    const float* __restrict__ hsumsq,
                                                    const float* __restrict__ hg,
                                                    const float* __restrict__ hbe,
                                                    u16* __restrict__ Z2){
  __shared__ __align__(16) u16 Hs[8*1024];
  __shared__ float bnS[1024], bnB[1024];
  __shared__ float v0s[1024], u1s[1024];
  __shared__ float Ps[256], qs[256], t1s[256], ss[256];
  __shared__ float ab0s[32];
  int tid = threadIdx.x;
  int r = tid >> 5, j = tid & 31;
  size_t row0 = (size_t)blockIdx.x * 8;

  for (int k = tid; k < 1024; k += 256){
    float mean = hsums[k] * (1.f/(float)BATCH);
    float var  = hsumsq[k] * (1.f/(float)BATCH) - mean*mean;
    float sc   = hg[k] * rsqrtf(var + 1e-5f);
    bnS[k] = sc;
    bnB[k] = hbe[k] - mean*sc;
    v0s[k] = v0[k]; u1s[k] = u1[k];
  }
  if (tid < 32) ab0s[tid] = ab0[tid];
  Ps[tid] = b2f(P[row0*32 + tid]);
  __syncthreads();
  for (int k = tid; k < 8*1024; k += 256){
    int col = k & 1023;
    float v = b2f(H[row0*1024 + k]) * bnS[col] + bnB[col];
    Hs[k] = f2b(v > 0.f ? v : 0.f);
  }
  __syncthreads();

  float acc = 0.f;
#pragma unroll
  for (int i=0;i<32;i++) acc += Ps[r*32+i] * b2f(Hs[r*1024 + i*32 + j]);
  qs[r*32+j] = acc;
  __syncthreads();

  acc = ab0s[j];
#pragma unroll
  for (int i=0;i<32;i++) acc += qs[r*32+i] * v0s[i*32+j];
  t1s[r*32+j] = 1.f / (1.f + __expf(-acc));
  __syncthreads();

  acc = 0.f;
#pragma unroll
  for (int i=0;i<32;i++) acc += t1s[r*32+i] * u1s[i*32+j];
  ss[r*32+j] = acc;
  __syncthreads();

  acc = 0.f;
#pragma unroll
  for (int i=0;i<32;i++) acc += ss[r*32+i] * b2f(Hs[r*1024 + i*32 + j]);
  Z2[(row0 + r)*32 + j] = f2b(acc);
}

// ---------------- final head: cross on e + inline BN(T,unbiased) + BN/ReLU(Mout) + LR ----
__global__ __launch_bounds__(256) void final_kernel(const u16* __restrict__ e,
                                                    const float* __restrict__ cw,
                                                    const float* __restrict__ cb,
                                                    const u16* __restrict__ t,
                                                    const u16* __restrict__ mo,
                                                    const float* __restrict__ tsums,
                                                    const float* __restrict__ tsumsq,
                                                    const float* __restrict__ tg,
                                                    const float* __restrict__ tbe,
                                                    const float* __restrict__ msums,
                                                    const float* __restrict__ msumsq,
                                                    const float* __restrict__ mg,
                                                    const float* __restrict__ mbe,
                                                    const float* __restrict__ lw,
                                                    const float* __restrict__ lb,
                                                    float* __restrict__ out){
  __shared__ float tS[256], tB[256], mS[256], mB[256];
  int tid = threadIdx.x;
  {
    int c = tid;
    float mean = tsums[c] * (1.f/(float)BATCH);
    float var  = (tsumsq[c] - mean*mean*(float)BATCH) * (1.f/(float)(BATCH-1));
    float sc   = tg[c] * rsqrtf(var + 1e-5f);
    tS[c] = sc; tB[c] = tbe[c] - mean*sc;
    float mmean = msums[c] * (1.f/(float)BATCH);
    float mvar  = msumsq[c] * (1.f/(float)BATCH) - mmean*mmean;
    float msc   = mg[c] * rsqrtf(mvar + 1e-5f);
    mS[c] = msc; mB[c] = mbe[c] - mmean*msc;
  }
  __syncthreads();
  int wave = tid >> 6, lane = tid & 63;
  int b = blockIdx.x*4 + wave;
  int n4 = lane*4;
  ushort4 ev = *(const ushort4*)(e + (size_t)b*256 + n4);
  float ec[4] = { b2f(ev.x), b2f(ev.y), b2f(ev.z), b2f(ev.w) };
  float x[4]  = { ec[0], ec[1], ec[2], ec[3] };
  for (int i=0;i<3;i++){
    float p = 0.f;
#pragma unroll
    for (int q=0;q<4;q++) p += x[q] * cw[i*256 + n4 + q];
#pragma unroll
    for (int o=1;o<64;o<<=1) p += __shfl_xor(p, o, 64);
#pragma unroll
    for (int q=0;q<4;q++) x[q] = ec[q]*p + cb[i*256 + n4 + q] + x[q];
  }
  ushort4 tv = *(const ushort4*)(t  + (size_t)b*256 + n4);
  ushort4 mv = *(const ushort4*)(mo + (size_t)b*256 + n4);
  float ta[4] = { b2f(tv.x), b2f(tv.y), b2f(tv.z), b2f(tv.w) };
  float ma[4] = { b2f(mv.x), b2f(mv.y), b2f(mv.z), b2f(mv.w) };
  float p = 0.f;
#pragma unroll
  for (int q=0;q<4;q++){
    int n = n4 + q;
    p += x[q] * lw[n];
    float mr = ma[q]*mS[n] + mB[n];
    mr = mr > 0.f ? mr : 0.f;
    float mf = tS[n]*ta[q] + tB[n] + mr;
    p += mf * lw[256 + n];
  }
#pragma unroll
  for (int o=32;o>0;o>>=1) p += __shfl_down(p, o, 64);
  if (lane == 0){
    float y = p + lb[0];
    out[b] = 1.f / (1.f + __expf(-y));
  }
}

extern "C" void kernel_launch(void* const* d_in, const int* in_sizes, int n_in,
                              void* d_out, int out_size, void* d_ws, size_t ws_size,
                              hipStream_t stream) {
  const int B = BATCH;
  const int*   feat = (const int*)d_in[0];
  const float* emb  = (const float*)d_in[2];
  const float* hW0 = (const float*)d_in[3],  *hb0 = (const float*)d_in[4],  *hg0 = (const float*)d_in[5],  *hbe0 = (const float*)d_in[6];
  const float* hW1 = (const float*)d_in[7],  *hb1 = (const float*)d_in[8],  *hg1 = (const float*)d_in[9],  *hbe1 = (const float*)d_in[10];
  const float* hW2 = (const float*)d_in[11], *hb2 = (const float*)d_in[12], *hg2 = (const float*)d_in[13], *hbe2 = (const float*)d_in[14];
  const float* cw  = (const float*)d_in[15], *cb  = (const float*)d_in[16];
  const float* mW0 = (const float*)d_in[17], *mb0 = (const float*)d_in[18], *mg0 = (const float*)d_in[19], *mbe0 = (const float*)d_in[20];
  const float* mW1 = (const float*)d_in[21], *mb1 = (const float*)d_in[22], *mg1 = (const float*)d_in[23], *mbe1 = (const float*)d_in[24];
  const float* u0  = (const float*)d_in[25], *u1  = (const float*)d_in[26];
  const float* v0  = (const float*)d_in[27], *v1  = (const float*)d_in[28];
  const float* ab0 = (const float*)d_in[29], *ab1 = (const float*)d_in[30];
  const float* gamma1 = (const float*)d_in[31], *bias1 = (const float*)d_in[32];
  const float* lw  = (const float*)d_in[33], *lb = (const float*)d_in[34];
  float* out = (float*)d_out;

  // ---- aliased workspace (~64.4 MB) ----
  // [ 0M,32M): H (live until adapter_core)
  // [32M,40M): e (live until final)
  // [40M,56M): Y0[40M)+Y1[44M) -> M0 -> T[40M,48M)+P[48M,49M)+Z2[49M,50M)
  // [56M,64M): {hW0t,hW1t,hW2t,mW0t} (dead before Mout gemm) -> Mout
  // [64M,+48K): stats | [64M+64K,+352K): mW1t, u0t, v1t
  char* base = (char*)d_ws;
  const size_t MB = 1024*1024;
  u16* H    = (u16*)(base);
  u16* e    = (u16*)(base + 32*MB);
  u16* Y0   = (u16*)(base + 40*MB);
  u16* Y1   = (u16*)(base + 44*MB);
  u16* M0   = (u16*)(base + 40*MB);
  u16* T    = (u16*)(base + 40*MB);
  u16* P    = (u16*)(base + 48*MB);
  u16* Z2   = (u16*)(base + 49*MB);
  u16* Mout = (u16*)(base + 56*MB);
  u16* hW0t = (u16*)(base + 56*MB);          // 32768 el
  u16* hW1t = hW0t + 32768;                  // 8192
  u16* hW2t = hW1t + 8192;                   // 65536
  u16* mW0t = hW2t + 65536;                  // 131072
  float* S  = (float*)(base + 64*MB);        // 6 layers x [1024 sums | 1024 sumsq]
  auto sums  = [&](int l){ return S + l*2048; };
  auto sumsq = [&](int l){ return S + l*2048 + 1024; };
  u16* mW1t = (u16*)(base + 64*MB + 64*1024);    // 131072 el
  u16* u0t  = mW1t + 131072;                 // 8192
  u16* v1t  = u0t + 8192;                    // 8192

  // 1. prep: zero stats + transpose weights + gather (one launch)
  prep_kernel<<<17936, 256, 0, stream>>>(S, hW0, hW1, hW2, mW0, mW1, u0, v1,
                                         hW0t, hW1t, hW2t, mW0t, mW1t, u0t, v1t,
                                         feat, emb, e);

  // 2. hyper chain -> H (BN applied inline in consumer from raw stats)
  gemm_mfma<<<dim3(2, B/64), 256, 0, stream>>>(e,  hW0t, hb0, Y0,
      nullptr, nullptr, nullptr, nullptr, sums(0), sumsq(0), 128, 256);
  gemm_mfma<<<dim3(1, B/64), 256, 0, stream>>>(Y0, hW1t, hb1, Y1,
      sums(0), sumsq(0), hg0, hbe0, sums(1), sumsq(1), 64, 128);
  gemm_mfma<<<dim3(16, B/64), 256, 0, stream>>>(Y1, hW2t, hb2, H,
      sums(1), sumsq(1), hg1, hbe1, sums(2), sumsq(2), 1024, 64);

  // 3. MLP chain
  gemm_mfma<<<dim3(8, B/64), 256, 0, stream>>>(e,  mW0t, mb0, M0,
      nullptr, nullptr, nullptr, nullptr, sums(3), sumsq(3), 512, 256);
  gemm_mfma<<<dim3(4, B/64), 256, 0, stream>>>(M0, mW1t, mb1, Mout,
      sums(3), sumsq(3), mg0, mbe0, sums(4), sumsq(4), 256, 512);

  // 4. adapter: P = BN_relu(Mout)@u0 ; core -> Z2 ; T = Z2@v1t + ab1 (stats fused)
  gemm_mfma<<<dim3(1, B/64), 256, 0, stream>>>(Mout, u0t, nullptr, P,
      sums(4), sumsq(4), mg1, mbe1, nullptr, nullptr, 32, 256);
  adapter_core<<<B/8, 256, 0, stream>>>(H, P, v0, u1, ab0,
      sums(2), sumsq(2), hg2, hbe2, Z2);
  gemm_mfma<<<dim3(4, B/64), 256, 0, stream>>>(Z2, v1t, ab1, T,
      nullptr, nullptr, nullptr, nullptr, sums(5), sumsq(5), 256, 32);

  // 5. final head (cross fused in, BN tables computed inline)
  final_kernel<<<B/4, 256, 0, stream>>>(e, cw, cb, T, Mout,
      sums(5), sumsq(5), gamma1, bias1,
      sums(4), sumsq(4), mg1, mbe1, lw, lb, out);
}